// Round 2
// baseline (50.251 us; speedup 1.0000x reference)
//
#include <hip/hip_runtime.h>
#include <math.h>

// Problem constants (from reference): B=16, T=2048, N=1024, Ttot=32768
#define NNEUR  1024
#define NCHUNK 256            // time chunks of 128 steps
#define SUBLEN 32             // time steps per thread (4 sub-chunks per block)
#define NC4    (NNEUR / 4)    // 256 float4 columns per time row

struct SegState { float cnt, first, last, g2; };

// Associative combine of two time-adjacent segments' ISI state.
__device__ __forceinline__ SegState seg_combine(const SegState& a, const SegState& b) {
    if (a.cnt == 0.0f) return b;
    if (b.cnt == 0.0f) return a;
    SegState r;
    float gap = b.first - a.last;   // crossing ISI
    r.cnt   = a.cnt + b.cnt;
    r.first = a.first;
    r.last  = b.last;
    r.g2    = a.g2 + b.g2 + gap * gap;
    return r;
}

// Kernel 1: streaming segmented scan over the 134 MB spike train.
// grid = (NNEUR/256, NCHUNK), block = 256.
// ccol = tid&63 -> float4 column (4 neurons); ysl = tid>>6 -> 32-step sub-chunk.
__global__ __launch_bounds__(256) void k_scan(const float* __restrict__ s,
                                              float4* __restrict__ wstate,
                                              unsigned int* __restrict__ counter) {
    // Deterministically reset the finalize counter every call (visible to the
    // next kernel at the dispatch boundary).
    if (blockIdx.x == 0 && blockIdx.y == 0 && threadIdx.x == 0) *counter = 0u;

    const int tid  = threadIdx.x;
    const int ccol = tid & 63;
    const int ysl  = tid >> 6;
    const int col4 = blockIdx.x * 64 + ccol;
    const int t0   = blockIdx.y * 128 + ysl * 32;

    const uint4* s4 = reinterpret_cast<const uint4*>(s);

    float cnt[4]   = {0.f, 0.f, 0.f, 0.f};
    float first[4] = {-1.f, -1.f, -1.f, -1.f};
    float last[4]  = {-1.f, -1.f, -1.f, -1.f};
    float g2[4]    = {0.f, 0.f, 0.f, 0.f};

    #pragma unroll
    for (int i = 0; i < SUBLEN; ++i) {
        const uint4 v = s4[(size_t)(t0 + i) * NC4 + col4];   // coalesced 1 KiB/wave
        const float tt = (float)(t0 + i);
        unsigned int bv[4] = {v.x, v.y, v.z, v.w};
        #pragma unroll
        for (int j = 0; j < 4; ++j) {
            // Branchless: spikes are exactly 0.0f or 1.0f, so uint != 0 is the mask.
            const bool  sp  = bv[j] != 0u;
            const bool  has = cnt[j] > 0.0f;
            const float g   = tt - last[j];
            g2[j]    = (sp && has)  ? fmaf(g, g, g2[j]) : g2[j];
            first[j] = (sp && !has) ? tt : first[j];
            last[j]  = sp ? tt : last[j];
            cnt[j]   = sp ? cnt[j] + 1.0f : cnt[j];
        }
    }

    // Time-ordered combine of the 4 sub-chunks per neuron via LDS.
    __shared__ float4 lds[4][64][4];   // 16 KiB
    #pragma unroll
    for (int j = 0; j < 4; ++j)
        lds[ysl][ccol][j] = make_float4(cnt[j], first[j], last[j], g2[j]);
    __syncthreads();

    if (ysl == 0) {
        #pragma unroll
        for (int j = 0; j < 4; ++j) {
            float4 a = lds[0][ccol][j];
            SegState st = {a.x, a.y, a.z, a.w};
            #pragma unroll
            for (int y = 1; y < 4; ++y) {
                float4 b = lds[y][ccol][j];
                SegState sb = {b.x, b.y, b.z, b.w};
                st = seg_combine(st, sb);
            }
            wstate[(size_t)blockIdx.y * NNEUR + col4 * 4 + j] =
                make_float4(st.cnt, st.first, st.last, st.g2);
        }
    }
}

// Kernel 2: per-neuron combine over NCHUNK chunk states + CV finalize + fused
// deterministic final reduction (last-block-done pattern).
// grid = 256 blocks, one wave (64 lanes) per neuron, 4 neurons per block.
__global__ __launch_bounds__(256) void k_finalize(const float4* __restrict__ wstate,
                                                  const float* __restrict__ target,
                                                  float* __restrict__ outsq,
                                                  float* __restrict__ outvalid,
                                                  unsigned int* __restrict__ counter,
                                                  float* __restrict__ out) {
    const int tid  = threadIdx.x;
    const int lane = tid & 63;
    const int w    = tid >> 6;
    const int n    = blockIdx.x * 4 + w;

    SegState st = {0.f, -1.f, -1.f, 0.f};
    #pragma unroll
    for (int j = 0; j < 4; ++j) {
        int c = lane * 4 + j;                       // ascending time order per lane
        float4 a = wstate[(size_t)c * NNEUR + n];
        SegState sb = {a.x, a.y, a.z, a.w};
        st = seg_combine(st, sb);
    }
    // Order-preserving binary tree across the 64 lanes.
    for (int off = 1; off < 64; off <<= 1) {
        SegState o;
        o.cnt   = __shfl_down(st.cnt,   off);
        o.first = __shfl_down(st.first, off);
        o.last  = __shfl_down(st.last,  off);
        o.g2    = __shfl_down(st.g2,    off);
        if ((lane & (2 * off - 1)) == 0) st = seg_combine(st, o);
    }

    if (lane == 0) {
        float k     = st.cnt;
        float n_isi = k - 1.0f;
        float sum_g = (k > 0.0f) ? (st.last - st.first) : 0.0f;  // telescoped sum of gaps
        float mean  = sum_g / fmaxf(n_isi, 1.0f);
        float var   = (st.g2 - n_isi * mean * mean) / fmaxf(n_isi - 1.0f, 1.0f);
        float sd    = sqrtf(fmaxf(var, 0.0f));
        bool valid  = (k >= 3.0f) && (mean > 0.0f);
        float cv    = valid ? sd / mean : 0.0f;
        float d     = cv - target[n];
        outsq[n]    = valid ? d * d : 0.0f;
        outvalid[n] = valid ? 1.0f : 0.0f;
        __threadfence();   // publish before the arrival atomic
    }
    __syncthreads();

    __shared__ unsigned int oldc;
    if (tid == 0) oldc = atomicAdd(counter, 1u);   // device-scope by default
    __syncthreads();

    if (oldc == gridDim.x - 1) {                   // uniform across the block
        __threadfence();                           // acquire other blocks' stores
        float ssum = 0.f, vsum = 0.f;
        for (int i = tid; i < NNEUR; i += 256) { ssum += outsq[i]; vsum += outvalid[i]; }
        for (int off = 32; off > 0; off >>= 1) {
            ssum += __shfl_down(ssum, off);
            vsum += __shfl_down(vsum, off);
        }
        __shared__ float ls[4], lv[4];
        if (lane == 0) { ls[w] = ssum; lv[w] = vsum; }
        __syncthreads();
        if (tid == 0) {
            float S = ls[0] + ls[1] + ls[2] + ls[3];
            float V = lv[0] + lv[1] + lv[2] + lv[3];
            out[0] = (V > 0.0f) ? S / fmaxf(V, 1.0f) : 0.0f;
        }
    }
}

extern "C" void kernel_launch(void* const* d_in, const int* in_sizes, int n_in,
                              void* d_out, int out_size, void* d_ws, size_t ws_size,
                              hipStream_t stream) {
    const float* spikes = (const float*)d_in[0];   // (B*T*N) fp32, exactly 0.0/1.0
    const float* target = (const float*)d_in[1];   // (N,) fp32
    float* out = (float*)d_out;

    // Workspace layout:
    //  [0, 4MB)        : float4 wstate[NCHUNK * NNEUR]
    //  [+4KB)          : float outsq[NNEUR]
    //  [+4KB)          : float outvalid[NNEUR]
    //  [+4B]           : unsigned int counter
    char* wsb = (char*)d_ws;
    float4* wstate   = (float4*)wsb;
    float*  outsq    = (float*)(wsb + (size_t)NCHUNK * NNEUR * sizeof(float4));
    float*  outvalid = outsq + NNEUR;
    unsigned int* counter = (unsigned int*)(outvalid + NNEUR);

    dim3 g1(NNEUR / 256, NCHUNK);
    k_scan<<<g1, 256, 0, stream>>>(spikes, wstate, counter);
    k_finalize<<<NNEUR / 4, 256, 0, stream>>>(wstate, target, outsq, outvalid, counter, out);
}

// Round 3
// 40.981 us; speedup vs baseline: 1.2262x; 1.2262x over previous
//
#include <hip/hip_runtime.h>
#include <math.h>

// Problem constants (from reference): B=16, T=2048, N=1024, Ttot=32768
#define TTOT   32768
#define NNEUR  1024
#define NCHUNK 512            // time chunks of 64 steps each
#define SUBLEN 16             // time steps per thread (4 sub-chunks per block)
#define NC4    (NNEUR / 4)    // 256 float4 columns per time row

struct SegState { float cnt, first, last, g2; };

// Associative combine of two time-adjacent segments' ISI state.
__device__ __forceinline__ SegState seg_combine(const SegState& a, const SegState& b) {
    if (a.cnt == 0.0f) return b;
    if (b.cnt == 0.0f) return a;
    SegState r;
    float gap = b.first - a.last;   // crossing ISI
    r.cnt   = a.cnt + b.cnt;
    r.first = a.first;
    r.last  = b.last;
    r.g2    = a.g2 + b.g2 + gap * gap;
    return r;
}

// Kernel 1: streaming segmented scan over the 134 MB spike train.
// grid = (NNEUR/256, NCHUNK), block = 256.
// ccol = tid&63 -> float4 column (4 neurons); ysl = tid>>6 -> 16-step sub-chunk.
__global__ __launch_bounds__(256) void k_scan(const float* __restrict__ s,
                                              float4* __restrict__ wstate) {
    const int tid  = threadIdx.x;
    const int ccol = tid & 63;
    const int ysl  = tid >> 6;
    const int col4 = blockIdx.x * 64 + ccol;       // float4 column index
    const int t0   = blockIdx.y * 64 + ysl * SUBLEN;

    const float4* s4 = reinterpret_cast<const float4*>(s);

    float cnt[4]   = {0.f, 0.f, 0.f, 0.f};
    float first[4] = {-1.f, -1.f, -1.f, -1.f};
    float last[4]  = {-1.f, -1.f, -1.f, -1.f};
    float g2[4]    = {0.f, 0.f, 0.f, 0.f};

    #pragma unroll
    for (int i = 0; i < SUBLEN; ++i) {
        const int t = t0 + i;
        const float4 v = s4[(size_t)t * NC4 + col4];   // coalesced 1 KiB/wave
        const float tt = (float)t;
        float vals[4] = {v.x, v.y, v.z, v.w};
        #pragma unroll
        for (int j = 0; j < 4; ++j) {
            if (vals[j] > 0.0f) {
                if (cnt[j] > 0.0f) {
                    float g = tt - last[j];
                    g2[j] += g * g;
                } else {
                    first[j] = tt;
                }
                last[j] = tt;
                cnt[j] += 1.0f;
            }
        }
    }

    // Time-ordered combine of the 4 sub-chunks per neuron via LDS.
    __shared__ float4 lds[4][64][4];   // 16 KiB
    #pragma unroll
    for (int j = 0; j < 4; ++j)
        lds[ysl][ccol][j] = make_float4(cnt[j], first[j], last[j], g2[j]);
    __syncthreads();

    if (ysl == 0) {
        #pragma unroll
        for (int j = 0; j < 4; ++j) {
            float4 a = lds[0][ccol][j];
            SegState st = {a.x, a.y, a.z, a.w};
            #pragma unroll
            for (int y = 1; y < 4; ++y) {
                float4 b = lds[y][ccol][j];
                SegState sb = {b.x, b.y, b.z, b.w};
                st = seg_combine(st, sb);
            }
            wstate[(size_t)blockIdx.y * NNEUR + col4 * 4 + j] =
                make_float4(st.cnt, st.first, st.last, st.g2);
        }
    }
}

// Kernel 2: per-neuron combine across NCHUNK chunk-states + finalize CV.
// One wave (64 lanes) per neuron; block = 256 threads = 4 neurons.
__global__ __launch_bounds__(256) void k_combine(const float4* __restrict__ wstate,
                                                 const float* __restrict__ target,
                                                 float* __restrict__ outsq,
                                                 float* __restrict__ outvalid) {
    const int tid  = threadIdx.x;
    const int lane = tid & 63;
    const int w    = tid >> 6;
    const int n    = blockIdx.x * 4 + w;

    SegState st = {0.f, -1.f, -1.f, 0.f};
    #pragma unroll
    for (int j = 0; j < NCHUNK / 64; ++j) {
        int c = lane * (NCHUNK / 64) + j;          // ascending time order per lane
        float4 a = wstate[(size_t)c * NNEUR + n];
        SegState sb = {a.x, a.y, a.z, a.w};
        st = seg_combine(st, sb);
    }
    // Order-preserving binary tree reduction across 64 lanes.
    for (int off = 1; off < 64; off <<= 1) {
        SegState o;
        o.cnt   = __shfl_down(st.cnt,   off);
        o.first = __shfl_down(st.first, off);
        o.last  = __shfl_down(st.last,  off);
        o.g2    = __shfl_down(st.g2,    off);
        if ((lane & (2 * off - 1)) == 0) st = seg_combine(st, o);
    }

    if (lane == 0) {
        float k     = st.cnt;
        float n_isi = k - 1.0f;
        float sum_g = (k > 0.0f) ? (st.last - st.first) : 0.0f;  // telescoped gap sum
        float mean  = sum_g / fmaxf(n_isi, 1.0f);
        float var   = (st.g2 - n_isi * mean * mean) / fmaxf(n_isi - 1.0f, 1.0f);
        float sd    = sqrtf(fmaxf(var, 0.0f));
        bool valid  = (k >= 3.0f) && (mean > 0.0f);
        float cv    = valid ? sd / mean : 0.0f;
        float d     = cv - target[n];
        outsq[n]    = valid ? d * d : 0.0f;
        outvalid[n] = valid ? 1.0f : 0.0f;
    }
}

// Kernel 3: deterministic reduction of 1024 per-neuron values -> scalar loss.
__global__ __launch_bounds__(256) void k_reduce(const float* __restrict__ outsq,
                                                const float* __restrict__ outvalid,
                                                float* __restrict__ out) {
    const int tid = threadIdx.x;
    float s = 0.f, v = 0.f;
    for (int i = tid; i < NNEUR; i += 256) {
        s += outsq[i];
        v += outvalid[i];
    }
    for (int off = 32; off > 0; off >>= 1) {
        s += __shfl_down(s, off);
        v += __shfl_down(v, off);
    }
    __shared__ float ls[4], lv[4];
    const int w = tid >> 6;
    if ((tid & 63) == 0) { ls[w] = s; lv[w] = v; }
    __syncthreads();
    if (tid == 0) {
        float S = ls[0] + ls[1] + ls[2] + ls[3];
        float V = lv[0] + lv[1] + lv[2] + lv[3];
        out[0] = (V > 0.0f) ? S / fmaxf(V, 1.0f) : 0.0f;
    }
}

extern "C" void kernel_launch(void* const* d_in, const int* in_sizes, int n_in,
                              void* d_out, int out_size, void* d_ws, size_t ws_size,
                              hipStream_t stream) {
    const float* spikes = (const float*)d_in[0];   // (B*T*N) fp32
    const float* target = (const float*)d_in[1];   // (N,) fp32
    float* out = (float*)d_out;

    // Workspace layout:
    //  [0, 8MB)   : float4 wstate[NCHUNK * NNEUR]
    //  [+4KB)     : float outsq[NNEUR]
    //  [+4KB)     : float outvalid[NNEUR]
    char* wsb = (char*)d_ws;
    float4* wstate   = (float4*)wsb;
    float*  outsq    = (float*)(wsb + (size_t)NCHUNK * NNEUR * sizeof(float4));
    float*  outvalid = outsq + NNEUR;

    dim3 g1(NNEUR / 256, NCHUNK);
    k_scan<<<g1, 256, 0, stream>>>(spikes, wstate);
    k_combine<<<NNEUR / 4, 256, 0, stream>>>(wstate, target, outsq, outvalid);
    k_reduce<<<1, 256, 0, stream>>>(outsq, outvalid, out);
}

// Round 4
// 35.648 us; speedup vs baseline: 1.4097x; 1.1496x over previous
//
#include <hip/hip_runtime.h>
#include <math.h>

// Problem constants (from reference): B=16, T=2048, N=1024, Ttot=32768
#define TTOT     32768
#define NNEUR    1024
#define NCHUNK   64           // time chunks of 512 steps each
#define CHUNKLEN 512
#define SUBLEN   32           // time steps per thread (16 sub-waves per block)
#define NC4      (NNEUR / 4)  // 256 float4 columns per time row

struct SegState { float cnt, first, last, g2; };

// Associative combine of two time-adjacent segments' ISI state.
__device__ __forceinline__ SegState seg_combine(const SegState& a, const SegState& b) {
    if (a.cnt == 0.0f) return b;
    if (b.cnt == 0.0f) return a;
    SegState r;
    float gap = b.first - a.last;   // crossing ISI
    r.cnt   = a.cnt + b.cnt;
    r.first = a.first;
    r.last  = b.last;
    r.g2    = a.g2 + b.g2 + gap * gap;
    return r;
}

// Kernel 1: streaming segmented scan over the 134 MB spike train.
// grid = (NNEUR/256, NCHUNK) = (4, 64) = 256 blocks (1 per CU), block = 1024
// (16 waves/CU). ccol = tid&63 -> float4 column (4 neurons);
// ysl = tid>>6 in [0,16) -> 32-step sub-chunk. Main loop identical to round 1.
__global__ __launch_bounds__(1024) void k_scan(const float* __restrict__ s,
                                               float4* __restrict__ wstate) {
    const int tid  = threadIdx.x;
    const int ccol = tid & 63;
    const int ysl  = tid >> 6;
    const int col4 = blockIdx.x * 64 + ccol;                 // float4 column index
    const int t0   = blockIdx.y * CHUNKLEN + ysl * SUBLEN;

    const float4* s4 = reinterpret_cast<const float4*>(s);

    float cnt[4]   = {0.f, 0.f, 0.f, 0.f};
    float first[4] = {-1.f, -1.f, -1.f, -1.f};
    float last[4]  = {-1.f, -1.f, -1.f, -1.f};
    float g2[4]    = {0.f, 0.f, 0.f, 0.f};

    #pragma unroll 4
    for (int i = 0; i < SUBLEN; ++i) {
        const int t = t0 + i;
        const float4 v = s4[(size_t)t * NC4 + col4];         // coalesced 1 KiB/wave
        const float tt = (float)t;
        float vals[4] = {v.x, v.y, v.z, v.w};
        #pragma unroll
        for (int j = 0; j < 4; ++j) {
            if (vals[j] > 0.0f) {
                if (cnt[j] > 0.0f) {
                    float g = tt - last[j];
                    g2[j] += g * g;
                } else {
                    first[j] = tt;
                }
                last[j] = tt;
                cnt[j] += 1.0f;
            }
        }
    }

    // SoA LDS: [ysl][j][ccol] -> lane-stride 4B = conflict-free writes,
    // <=4-way conflicts on the epilogue reads. 4 x 16 KiB = 64 KiB.
    __shared__ float lcnt[16][4][64], lfirst[16][4][64], llast[16][4][64], lg2[16][4][64];
    #pragma unroll
    for (int j = 0; j < 4; ++j) {
        lcnt  [ysl][j][ccol] = cnt[j];
        lfirst[ysl][j][ccol] = first[j];
        llast [ysl][j][ccol] = last[j];
        lg2   [ysl][j][ccol] = g2[j];
    }
    __syncthreads();

    // Epilogue over 4 waves: thread tid<256 owns neuron blockIdx.x*256 + tid,
    // combines its 16 sub-chunk states in time order, writes coalesced.
    if (tid < 256) {
        const int c = tid >> 2;       // ccol of my neuron
        const int j = tid & 3;        // quad slot of my neuron
        SegState st = {lcnt[0][j][c], lfirst[0][j][c], llast[0][j][c], lg2[0][j][c]};
        #pragma unroll
        for (int y = 1; y < 16; ++y) {
            SegState b = {lcnt[y][j][c], lfirst[y][j][c], llast[y][j][c], lg2[y][j][c]};
            st = seg_combine(st, b);
        }
        wstate[(size_t)blockIdx.y * NNEUR + blockIdx.x * 256 + tid] =
            make_float4(st.cnt, st.first, st.last, st.g2);   // wave writes 1 KiB contiguous
    }
}

// Kernel 2: per-neuron combine across NCHUNK=64 chunk-states + finalize CV.
// One wave (64 lanes) per neuron, one chunk-state per lane; block = 4 neurons.
__global__ __launch_bounds__(256) void k_combine(const float4* __restrict__ wstate,
                                                 const float* __restrict__ target,
                                                 float* __restrict__ outsq,
                                                 float* __restrict__ outvalid) {
    const int tid  = threadIdx.x;
    const int lane = tid & 63;
    const int w    = tid >> 6;
    const int n    = blockIdx.x * 4 + w;

    float4 a = wstate[(size_t)lane * NNEUR + n];   // lane = chunk, ascending time
    SegState st = {a.x, a.y, a.z, a.w};

    // Order-preserving binary tree reduction across 64 lanes.
    for (int off = 1; off < 64; off <<= 1) {
        SegState o;
        o.cnt   = __shfl_down(st.cnt,   off);
        o.first = __shfl_down(st.first, off);
        o.last  = __shfl_down(st.last,  off);
        o.g2    = __shfl_down(st.g2,    off);
        if ((lane & (2 * off - 1)) == 0) st = seg_combine(st, o);
    }

    if (lane == 0) {
        float k     = st.cnt;
        float n_isi = k - 1.0f;
        float sum_g = (k > 0.0f) ? (st.last - st.first) : 0.0f;  // telescoped gap sum
        float mean  = sum_g / fmaxf(n_isi, 1.0f);
        float var   = (st.g2 - n_isi * mean * mean) / fmaxf(n_isi - 1.0f, 1.0f);
        float sd    = sqrtf(fmaxf(var, 0.0f));
        bool valid  = (k >= 3.0f) && (mean > 0.0f);
        float cv    = valid ? sd / mean : 0.0f;
        float d     = cv - target[n];
        outsq[n]    = valid ? d * d : 0.0f;
        outvalid[n] = valid ? 1.0f : 0.0f;
    }
}

// Kernel 3: deterministic reduction of 1024 per-neuron values -> scalar loss.
__global__ __launch_bounds__(256) void k_reduce(const float* __restrict__ outsq,
                                                const float* __restrict__ outvalid,
                                                float* __restrict__ out) {
    const int tid = threadIdx.x;
    float s = 0.f, v = 0.f;
    for (int i = tid; i < NNEUR; i += 256) {
        s += outsq[i];
        v += outvalid[i];
    }
    for (int off = 32; off > 0; off >>= 1) {
        s += __shfl_down(s, off);
        v += __shfl_down(v, off);
    }
    __shared__ float ls[4], lv[4];
    const int w = tid >> 6;
    if ((tid & 63) == 0) { ls[w] = s; lv[w] = v; }
    __syncthreads();
    if (tid == 0) {
        float S = ls[0] + ls[1] + ls[2] + ls[3];
        float V = lv[0] + lv[1] + lv[2] + lv[3];
        out[0] = (V > 0.0f) ? S / fmaxf(V, 1.0f) : 0.0f;
    }
}

extern "C" void kernel_launch(void* const* d_in, const int* in_sizes, int n_in,
                              void* d_out, int out_size, void* d_ws, size_t ws_size,
                              hipStream_t stream) {
    const float* spikes = (const float*)d_in[0];   // (B*T*N) fp32
    const float* target = (const float*)d_in[1];   // (N,) fp32
    float* out = (float*)d_out;

    // Workspace layout:
    //  [0, 1MB)   : float4 wstate[NCHUNK * NNEUR]
    //  [+4KB)     : float outsq[NNEUR]
    //  [+4KB)     : float outvalid[NNEUR]
    char* wsb = (char*)d_ws;
    float4* wstate   = (float4*)wsb;
    float*  outsq    = (float*)(wsb + (size_t)NCHUNK * NNEUR * sizeof(float4));
    float*  outvalid = outsq + NNEUR;

    dim3 g1(NNEUR / 256, NCHUNK);
    k_scan<<<g1, 1024, 0, stream>>>(spikes, wstate);
    k_combine<<<NNEUR / 4, 256, 0, stream>>>(wstate, target, outsq, outvalid);
    k_reduce<<<1, 256, 0, stream>>>(outsq, outvalid, out);
}

// Round 5
// 35.609 us; speedup vs baseline: 1.4112x; 1.0011x over previous
//
#include <hip/hip_runtime.h>
#include <math.h>

// Problem constants (from reference): B=16, T=2048, N=1024, Ttot=32768
#define TTOT   32768
#define NNEUR  1024
#define NCHUNK 256            // time chunks of 128 steps
#define SUBLEN 32             // time steps per thread (4 sub-chunks per block)
#define NC4    (NNEUR / 4)    // 256 float4 columns per time row
#define LBATCH 8              // loads kept in flight per wave

typedef float f32x4 __attribute__((ext_vector_type(4)));

struct SegState { float cnt, first, last, g2; };

// Associative combine of two time-adjacent segments' ISI state.
__device__ __forceinline__ SegState seg_combine(const SegState& a, const SegState& b) {
    if (a.cnt == 0.0f) return b;
    if (b.cnt == 0.0f) return a;
    SegState r;
    float gap = b.first - a.last;   // crossing ISI
    r.cnt   = a.cnt + b.cnt;
    r.first = a.first;
    r.last  = b.last;
    r.g2    = a.g2 + b.g2 + gap * gap;
    return r;
}

// Kernel 1: streaming segmented scan over the 134 MB spike train.
// grid = (NNEUR/256, NCHUNK) = (4,256), block = 256.
// ccol = tid&63 -> float4 column (4 neurons); ysl = tid>>6 -> 32-step sub-chunk.
// Inner loop is phase-split: 8 branch-free nontemporal loads (8 KB/wave in
// flight), then the branchy per-spike update on the registered batch.
__global__ __launch_bounds__(256) void k_scan(const float* __restrict__ s,
                                              float4* __restrict__ wstate) {
    const int tid  = threadIdx.x;
    const int ccol = tid & 63;
    const int ysl  = tid >> 6;
    const int col4 = blockIdx.x * 64 + ccol;       // float4 column index
    const int t0   = blockIdx.y * 128 + ysl * SUBLEN;

    const f32x4* s4 = reinterpret_cast<const f32x4*>(s);

    float cnt[4]   = {0.f, 0.f, 0.f, 0.f};
    float first[4] = {-1.f, -1.f, -1.f, -1.f};
    float last[4]  = {-1.f, -1.f, -1.f, -1.f};
    float g2[4]    = {0.f, 0.f, 0.f, 0.f};

    for (int g = 0; g < SUBLEN / LBATCH; ++g) {
        // Phase A: issue LBATCH independent 16B loads, no branches in between.
        f32x4 v[LBATCH];
        #pragma unroll
        for (int i = 0; i < LBATCH; ++i)
            v[i] = __builtin_nontemporal_load(
                &s4[(size_t)(t0 + g * LBATCH + i) * NC4 + col4]);

        // Phase B: branchy (exec-mask-skipped) sparse update on the batch.
        #pragma unroll
        for (int i = 0; i < LBATCH; ++i) {
            const float tt = (float)(t0 + g * LBATCH + i);
            #pragma unroll
            for (int j = 0; j < 4; ++j) {
                if (v[i][j] > 0.0f) {
                    if (cnt[j] > 0.0f) {
                        float gp = tt - last[j];
                        g2[j] += gp * gp;
                    } else {
                        first[j] = tt;
                    }
                    last[j] = tt;
                    cnt[j] += 1.0f;
                }
            }
        }
    }

    // Time-ordered combine of the 4 sub-chunks per neuron via LDS.
    __shared__ float4 lds[4][64][4];   // 16 KiB
    #pragma unroll
    for (int j = 0; j < 4; ++j)
        lds[ysl][ccol][j] = make_float4(cnt[j], first[j], last[j], g2[j]);
    __syncthreads();

    if (ysl == 0) {
        #pragma unroll
        for (int j = 0; j < 4; ++j) {
            float4 a = lds[0][ccol][j];
            SegState st = {a.x, a.y, a.z, a.w};
            #pragma unroll
            for (int y = 1; y < 4; ++y) {
                float4 b = lds[y][ccol][j];
                SegState sb = {b.x, b.y, b.z, b.w};
                st = seg_combine(st, sb);
            }
            wstate[(size_t)blockIdx.y * NNEUR + col4 * 4 + j] =
                make_float4(st.cnt, st.first, st.last, st.g2);
        }
    }
}

// Kernel 2: per-neuron combine across NCHUNK chunk-states + finalize CV.
// One wave (64 lanes) per neuron; block = 256 threads = 4 neurons.
__global__ __launch_bounds__(256) void k_combine(const float4* __restrict__ wstate,
                                                 const float* __restrict__ target,
                                                 float* __restrict__ outsq,
                                                 float* __restrict__ outvalid) {
    const int tid  = threadIdx.x;
    const int lane = tid & 63;
    const int w    = tid >> 6;
    const int n    = blockIdx.x * 4 + w;

    SegState st = {0.f, -1.f, -1.f, 0.f};
    #pragma unroll
    for (int j = 0; j < NCHUNK / 64; ++j) {
        int c = lane * (NCHUNK / 64) + j;          // ascending time order per lane
        float4 a = wstate[(size_t)c * NNEUR + n];
        SegState sb = {a.x, a.y, a.z, a.w};
        st = seg_combine(st, sb);
    }
    // Order-preserving binary tree reduction across 64 lanes.
    for (int off = 1; off < 64; off <<= 1) {
        SegState o;
        o.cnt   = __shfl_down(st.cnt,   off);
        o.first = __shfl_down(st.first, off);
        o.last  = __shfl_down(st.last,  off);
        o.g2    = __shfl_down(st.g2,    off);
        if ((lane & (2 * off - 1)) == 0) st = seg_combine(st, o);
    }

    if (lane == 0) {
        float k     = st.cnt;
        float n_isi = k - 1.0f;
        float sum_g = (k > 0.0f) ? (st.last - st.first) : 0.0f;  // telescoped gap sum
        float mean  = sum_g / fmaxf(n_isi, 1.0f);
        float var   = (st.g2 - n_isi * mean * mean) / fmaxf(n_isi - 1.0f, 1.0f);
        float sd    = sqrtf(fmaxf(var, 0.0f));
        bool valid  = (k >= 3.0f) && (mean > 0.0f);
        float cv    = valid ? sd / mean : 0.0f;
        float d     = cv - target[n];
        outsq[n]    = valid ? d * d : 0.0f;
        outvalid[n] = valid ? 1.0f : 0.0f;
    }
}

// Kernel 3: deterministic reduction of 1024 per-neuron values -> scalar loss.
__global__ __launch_bounds__(256) void k_reduce(const float* __restrict__ outsq,
                                                const float* __restrict__ outvalid,
                                                float* __restrict__ out) {
    const int tid = threadIdx.x;
    float s = 0.f, v = 0.f;
    for (int i = tid; i < NNEUR; i += 256) {
        s += outsq[i];
        v += outvalid[i];
    }
    for (int off = 32; off > 0; off >>= 1) {
        s += __shfl_down(s, off);
        v += __shfl_down(v, off);
    }
    __shared__ float ls[4], lv[4];
    const int w = tid >> 6;
    if ((tid & 63) == 0) { ls[w] = s; lv[w] = v; }
    __syncthreads();
    if (tid == 0) {
        float S = ls[0] + ls[1] + ls[2] + ls[3];
        float V = lv[0] + lv[1] + lv[2] + lv[3];
        out[0] = (V > 0.0f) ? S / fmaxf(V, 1.0f) : 0.0f;
    }
}

extern "C" void kernel_launch(void* const* d_in, const int* in_sizes, int n_in,
                              void* d_out, int out_size, void* d_ws, size_t ws_size,
                              hipStream_t stream) {
    const float* spikes = (const float*)d_in[0];   // (B*T*N) fp32
    const float* target = (const float*)d_in[1];   // (N,) fp32
    float* out = (float*)d_out;

    // Workspace layout:
    //  [0, 4MB)   : float4 wstate[NCHUNK * NNEUR]
    //  [+4KB)     : float outsq[NNEUR]
    //  [+4KB)     : float outvalid[NNEUR]
    char* wsb = (char*)d_ws;
    float4* wstate   = (float4*)wsb;
    float*  outsq    = (float*)(wsb + (size_t)NCHUNK * NNEUR * sizeof(float4));
    float*  outvalid = outsq + NNEUR;

    dim3 g1(NNEUR / 256, NCHUNK);
    k_scan<<<g1, 256, 0, stream>>>(spikes, wstate);
    k_combine<<<NNEUR / 4, 256, 0, stream>>>(wstate, target, outsq, outvalid);
    k_reduce<<<1, 256, 0, stream>>>(outsq, outvalid, out);
}